// Round 3
// baseline (1689.781 us; speedup 1.0000x reference)
//
#include <hip/hip_runtime.h>
#include <cstdint>

// Problem constants
#define BB   8
#define CC   19
#define HWP  524288          // H*W pixels per batch row
#define NPIX 4194304         // B*H*W
#define KSEL 131072          // int(0.25 * HWP)
#define GRID 4096            // blocks for the 3 wide kernels

// Native vector types accepted by __builtin_nontemporal_load
typedef float  fx4 __attribute__((ext_vector_type(4)));
typedef int    ix4 __attribute__((ext_vector_type(4)));

// ws layout:
//   [0, 16 MiB)  loss float[NPIX]
//   ctrl (u32 words, zeroed via hipMemsetAsync each launch):
#define H1_OFF   0                       // hist1: 8*2048
#define H2_OFF   (8*2048)                // hist2: 8*4096
#define H3_OFF   (H2_OFF + 8*4096)      // hist3: 8*256
#define SEL1_OFF (H3_OFF + 8*256)       // 51200
#define CNT1_OFF (SEL1_OFF + 8)
#define SEL2_OFF (CNT1_OFF + 8)
#define CNT2_OFF (SEL2_OFF + 8)
#define TKT_OFF  (CNT2_OFF + 8)         // 4 ticket counters
#define SUMA_OFF (TKT_OFF + 4)          // byte offset 204944 -> %8==0, double-aligned
#define CTRL_WORDS (SUMA_OFF + 16)      // 8 doubles = 16 words
#define LOSS_BYTES (NPIX * 4)

// ---------- block-level primitives ----------

__device__ __forceinline__ uint32_t block_incl_scan_u32(uint32_t v, volatile uint32_t* wt) {
    int lane = threadIdx.x & 63, wid = threadIdx.x >> 6;
    uint32_t inc = v;
#pragma unroll
    for (int off = 1; off < 64; off <<= 1) {
        uint32_t t = __shfl_up(inc, off);
        if (lane >= off) inc += t;
    }
    __syncthreads();                 // protect wt reuse across calls
    if (lane == 63) wt[wid] = inc;
    __syncthreads();
    for (int w = 0; w < wid; w++) inc += wt[w];
    return inc;
}

__device__ __forceinline__ double block_reduce_double(double v, volatile double* dwt) {
    int lane = threadIdx.x & 63, wid = threadIdx.x >> 6;
#pragma unroll
    for (int off = 32; off > 0; off >>= 1) v += __shfl_down(v, off);
    __syncthreads();
    if (lane == 0) dwt[wid] = v;
    __syncthreads();
    return dwt[0] + dwt[1] + dwt[2] + dwt[3];
}

// Parallel descending radix-select over per-row histograms (run by ONE block).
template <int NBINS>
__device__ void scan_rows(const uint32_t* __restrict__ hist,
                          const uint32_t* __restrict__ cntPrev,
                          uint32_t* __restrict__ selOut, uint32_t* __restrict__ cntOut,
                          volatile uint32_t* wt)
{
    constexpr int CH = NBINS / 256;
    for (int r = 0; r < BB; r++) {
        const uint32_t* hrow = hist + r * NBINS;
        int base = NBINS - CH * ((int)threadIdx.x + 1);   // thread 0 owns TOP bins
        uint32_t hloc[CH];
        uint32_t csum = 0;
#pragma unroll
        for (int i = 0; i < CH; i++) { hloc[i] = hrow[base + i]; csum += hloc[i]; }
        uint32_t incl = block_incl_scan_u32(csum, wt);
        uint32_t pre = incl - csum;                       // count strictly above my chunk
        uint32_t prev = cntPrev ? cntPrev[r] : 0u;
        uint32_t target = (uint32_t)KSEL - prev;
        if (pre < target && pre + csum >= target) {
            uint32_t cum = pre;
#pragma unroll
            for (int i = CH - 1; i >= 0; i--) {
                uint32_t h = hloc[i];
                if (cum + h >= target) { selOut[r] = (uint32_t)(base + i); cntOut[r] = prev + cum; break; }
                cum += h;
            }
        }
    }
}

__device__ __forceinline__ void block_sum_atomic(double sum, double* dst, volatile double* dwt) {
    double t = block_reduce_double(sum, dwt);
    if (threadIdx.x == 0 && t != 0.0) atomicAdd(dst, t);
}

// ---------- K1: fused CE loss + top-12-bit histogram + (last block) scan1 ----------

__global__ __launch_bounds__(256) void loss_hist1(
    const float* __restrict__ logits, const int* __restrict__ labels,
    float* __restrict__ loss, uint32_t* __restrict__ ctrl)
{
    __shared__ uint32_t lh[2048];
    __shared__ uint32_t wt[4];
    __shared__ uint32_t isLast;
    uint32_t* hist1 = ctrl + H1_OFF;

    for (int i = threadIdx.x; i < 2048; i += 256) lh[i] = 0u;
    __syncthreads();

    int b = blockIdx.x >> 9;
    int pix0 = blockIdx.x * 1024 + threadIdx.x * 4;
    int prow = pix0 & (HWP - 1);

    const fx4* lg = (const fx4*)(logits + (size_t)b * CC * HWP + prow);
    fx4 a[CC];
#pragma unroll
    for (int c = 0; c < CC; c++) a[c] = __builtin_nontemporal_load(&lg[(size_t)c * (HWP / 4)]);

    ix4 lab = __builtin_nontemporal_load((const ix4*)(labels + pix0));

    float mx0 = a[0].x, mx1 = a[0].y, mx2 = a[0].z, mx3 = a[0].w;
#pragma unroll
    for (int c = 1; c < CC; c++) {
        mx0 = fmaxf(mx0, a[c].x); mx1 = fmaxf(mx1, a[c].y);
        mx2 = fmaxf(mx2, a[c].z); mx3 = fmaxf(mx3, a[c].w);
    }
    float g0 = 0.f, g1 = 0.f, g2 = 0.f, g3 = 0.f;
    float e0 = 0.f, e1 = 0.f, e2 = 0.f, e3 = 0.f;
#pragma unroll
    for (int c = 0; c < CC; c++) {
        e0 += __expf(a[c].x - mx0); e1 += __expf(a[c].y - mx1);
        e2 += __expf(a[c].z - mx2); e3 += __expf(a[c].w - mx3);
        g0 = (lab.x == c) ? a[c].x : g0;
        g1 = (lab.y == c) ? a[c].y : g1;
        g2 = (lab.z == c) ? a[c].z : g2;
        g3 = (lab.w == c) ? a[c].w : g3;
    }
    // CE >= 0 mathematically; clamp guards the bit-histogram from sign-bit flukes.
    float l0 = fmaxf(mx0 + __logf(e0) - g0, 0.f);
    float l1 = fmaxf(mx1 + __logf(e1) - g1, 0.f);
    float l2 = fmaxf(mx2 + __logf(e2) - g2, 0.f);
    float l3 = fmaxf(mx3 + __logf(e3) - g3, 0.f);

    float4 o; o.x = l0; o.y = l1; o.z = l2; o.w = l3;
    *(float4*)(loss + pix0) = o;   // plain store: K2/K3 re-read, give L2 a chance

    atomicAdd(&lh[__float_as_uint(l0) >> 20], 1u);
    atomicAdd(&lh[__float_as_uint(l1) >> 20], 1u);
    atomicAdd(&lh[__float_as_uint(l2) >> 20], 1u);
    atomicAdd(&lh[__float_as_uint(l3) >> 20], 1u);

    __syncthreads();
    for (int i = threadIdx.x; i < 2048; i += 256) {
        uint32_t v = lh[i];
        if (v) atomicAdd(&hist1[b * 2048 + i], v);
    }

    // last-arriving block performs scan1 (rocPRIM-style ticket pattern)
    __threadfence();
    __syncthreads();
    if (threadIdx.x == 0) isLast = (atomicAdd(ctrl + TKT_OFF + 0, 1u) == GRID - 1);
    __syncthreads();
    if (isLast) {
        __threadfence();
        scan_rows<2048>(hist1, nullptr, ctrl + SEL1_OFF, ctrl + CNT1_OFF, wt);
    }
}

// ---------- K2: sum-above + mid-12-bit refine + (last block) scan2 ----------

__global__ __launch_bounds__(256) void refine2(
    const float* __restrict__ loss, uint32_t* __restrict__ ctrl)
{
    __shared__ uint32_t lh[4096];
    __shared__ uint32_t wt[4];
    __shared__ double dwt[4];
    __shared__ uint32_t isLast;
    uint32_t* hist2 = ctrl + H2_OFF;
    double* sumAbove = (double*)(ctrl + SUMA_OFF);

    for (int i = threadIdx.x; i < 4096; i += 256) lh[i] = 0u;
    __syncthreads();

    int b = blockIdx.x >> 9;
    uint32_t s1 = ctrl[SEL1_OFF + b];
    int pix0 = blockIdx.x * 1024 + threadIdx.x * 4;
    float4 v = *(const float4*)(loss + pix0);

    double sum = 0.0;
    {
        float vv[4] = {v.x, v.y, v.z, v.w};
#pragma unroll
        for (int j = 0; j < 4; j++) {
            uint32_t u = __float_as_uint(vv[j]);
            uint32_t t = u >> 20;
            if (t > s1) sum += (double)vv[j];
            else if (t == s1) atomicAdd(&lh[(u >> 8) & 0xFFFu], 1u);
        }
    }
    __syncthreads();
    block_sum_atomic(sum, &sumAbove[b], dwt);
    for (int i = threadIdx.x; i < 4096; i += 256) {
        uint32_t c = lh[i];
        if (c) atomicAdd(&hist2[b * 4096 + i], c);
    }

    __threadfence();
    __syncthreads();
    if (threadIdx.x == 0) isLast = (atomicAdd(ctrl + TKT_OFF + 1, 1u) == GRID - 1);
    __syncthreads();
    if (isLast) {
        __threadfence();
        scan_rows<4096>(hist2, ctrl + CNT1_OFF, ctrl + SEL2_OFF, ctrl + CNT2_OFF, wt);
    }
}

// ---------- K3: low-8-bit refine + (last block) exact closed-form finalize ----------

__global__ __launch_bounds__(256) void refine3(
    const float* __restrict__ loss, uint32_t* __restrict__ ctrl, float* __restrict__ out)
{
    __shared__ uint32_t lh[256];
    __shared__ uint32_t wt[4];
    __shared__ double dwt[4];
    __shared__ uint32_t isLast;
    uint32_t* hist3 = ctrl + H3_OFF;
    double* sumAbove = (double*)(ctrl + SUMA_OFF);

    lh[threadIdx.x] = 0u;
    __syncthreads();

    int b = blockIdx.x >> 9;
    uint32_t s1 = ctrl[SEL1_OFF + b], s2 = ctrl[SEL2_OFF + b];
    int pix0 = blockIdx.x * 1024 + threadIdx.x * 4;
    float4 v = *(const float4*)(loss + pix0);

    double sum = 0.0;
    {
        float vv[4] = {v.x, v.y, v.z, v.w};
#pragma unroll
        for (int j = 0; j < 4; j++) {
            uint32_t u = __float_as_uint(vv[j]);
            if ((u >> 20) == s1) {
                uint32_t mid = (u >> 8) & 0xFFFu;
                if (mid > s2) sum += (double)vv[j];
                else if (mid == s2) atomicAdd(&lh[u & 0xFFu], 1u);
            }
        }
    }
    __syncthreads();
    block_sum_atomic(sum, &sumAbove[b], dwt);
    {
        uint32_t c = lh[threadIdx.x];
        if (c) atomicAdd(&hist3[b * 256 + threadIdx.x], c);
    }

    __threadfence();
    __syncthreads();
    if (threadIdx.x == 0) isLast = (atomicAdd(ctrl + TKT_OFF + 2, 1u) == GRID - 1);
    __syncthreads();
    if (!isLast) return;
    __threadfence();

    // hist3 bins are EXACT float bit patterns -> closed-form tie-corrected sum.
    // Thread t owns bin b3 = 255 - t (top-first). Fully parallel, no serial walk.
    double tot = 0.0;
    for (int r = 0; r < BB; r++) {
        int b3 = 255 - (int)threadIdx.x;
        uint32_t h = hist3[r * 256 + b3];
        uint32_t incl = block_incl_scan_u32(h, wt);
        uint32_t pre = incl - h;                       // count in bins above b3
        uint32_t rem = (uint32_t)KSEL - ctrl[CNT2_OFF + r];
        uint32_t take = (rem > pre) ? ((rem - pre < h) ? (rem - pre) : h) : 0u;
        uint32_t P = (ctrl[SEL1_OFF + r] << 20) | (ctrl[SEL2_OFF + r] << 8) | (uint32_t)b3;
        double contrib = (double)take * (double)__uint_as_float(P);
        double s = block_reduce_double(contrib, dwt);
        if (threadIdx.x == 0) tot += s + sumAbove[r];
    }
    if (threadIdx.x == 0) out[0] = (float)(tot / ((double)BB * (double)KSEL));
}

extern "C" void kernel_launch(void* const* d_in, const int* in_sizes, int n_in,
                              void* d_out, int out_size, void* d_ws, size_t ws_size,
                              hipStream_t stream)
{
    const float* logits = (const float*)d_in[0];
    const int* labels   = (const int*)d_in[1];
    float* out          = (float*)d_out;

    char* ws = (char*)d_ws;
    float* loss    = (float*)ws;
    uint32_t* ctrl = (uint32_t*)(ws + LOSS_BYTES);

    (void)hipMemsetAsync(ctrl, 0, CTRL_WORDS * sizeof(uint32_t), stream);
    loss_hist1<<<GRID, 256, 0, stream>>>(logits, labels, loss, ctrl);
    refine2<<<GRID, 256, 0, stream>>>(loss, ctrl);
    refine3<<<GRID, 256, 0, stream>>>(loss, ctrl, out);
}

// Round 4
// 533.250 us; speedup vs baseline: 3.1688x; 3.1688x over previous
//
#include <hip/hip_runtime.h>
#include <cstdint>

// Problem constants
#define BB   8
#define CC   19
#define HWP  524288          // H*W pixels per batch row
#define NPIX 4194304         // B*H*W
#define KSEL 131072          // int(0.25 * HWP)
#define GRID 4096            // blocks for the 3 wide kernels

// ws layout:
//   [0, 16 MiB)  loss float[NPIX]
//   ctrl (u32 words, zeroed via hipMemsetAsync each launch):
#define H1_OFF   0                       // hist1: 8*2048
#define H2_OFF   (8*2048)                // hist2: 8*4096
#define H3_OFF   (H2_OFF + 8*4096)      // hist3: 8*256
#define SEL1_OFF (H3_OFF + 8*256)       // 51200
#define CNT1_OFF (SEL1_OFF + 8)
#define SEL2_OFF (CNT1_OFF + 8)
#define CNT2_OFF (SEL2_OFF + 8)
#define PAD_OFF  (CNT2_OFF + 8)         // 4 words pad
#define SUMA_OFF (PAD_OFF + 4)          // byte offset %8==0 -> double-aligned
#define CTRL_WORDS (SUMA_OFF + 16)      // 8 doubles = 16 words
#define LOSS_BYTES (NPIX * 4)

// ---------- block-level primitives (256 threads) ----------

__device__ __forceinline__ uint32_t block_incl_scan_u32(uint32_t v, volatile uint32_t* wt) {
    int lane = threadIdx.x & 63, wid = threadIdx.x >> 6;
    uint32_t inc = v;
#pragma unroll
    for (int off = 1; off < 64; off <<= 1) {
        uint32_t t = __shfl_up(inc, off);
        if (lane >= off) inc += t;
    }
    __syncthreads();                 // protect wt reuse across calls
    if (lane == 63) wt[wid] = inc;
    __syncthreads();
    for (int w = 0; w < wid; w++) inc += wt[w];
    return inc;
}

__device__ __forceinline__ double block_reduce_double(double v, volatile double* dwt) {
    int lane = threadIdx.x & 63, wid = threadIdx.x >> 6;
#pragma unroll
    for (int off = 32; off > 0; off >>= 1) v += __shfl_down(v, off);
    __syncthreads();
    if (lane == 0) dwt[wid] = v;
    __syncthreads();
    return dwt[0] + dwt[1] + dwt[2] + dwt[3];
}

__device__ __forceinline__ void block_sum_atomic(double sum, double* dst, volatile double* dwt) {
    double t = block_reduce_double(sum, dwt);
    if (threadIdx.x == 0 && t != 0.0) atomicAdd(dst, t);
}

// ---------- K1: fused CE loss + top-12-bit histogram ----------
// Plain (cached) loads; no device fences anywhere in this pipeline.

__global__ __launch_bounds__(256) void loss_hist1(
    const float* __restrict__ logits, const int* __restrict__ labels,
    float* __restrict__ loss, uint32_t* __restrict__ hist1)
{
    __shared__ uint32_t lh[2048];
    for (int i = threadIdx.x; i < 2048; i += 256) lh[i] = 0u;
    __syncthreads();

    int b = blockIdx.x >> 9;                       // 512 blocks per batch row
    int pix0 = blockIdx.x * 1024 + threadIdx.x * 4;
    int prow = pix0 & (HWP - 1);

    const float4* lg = (const float4*)(logits + (size_t)b * CC * HWP + prow);
    float4 a[CC];
#pragma unroll
    for (int c = 0; c < CC; c++) a[c] = lg[(size_t)c * (HWP / 4)];

    int4 lab = *(const int4*)(labels + pix0);

    float mx0 = a[0].x, mx1 = a[0].y, mx2 = a[0].z, mx3 = a[0].w;
#pragma unroll
    for (int c = 1; c < CC; c++) {
        mx0 = fmaxf(mx0, a[c].x); mx1 = fmaxf(mx1, a[c].y);
        mx2 = fmaxf(mx2, a[c].z); mx3 = fmaxf(mx3, a[c].w);
    }
    float g0 = 0.f, g1 = 0.f, g2 = 0.f, g3 = 0.f;
    float e0 = 0.f, e1 = 0.f, e2 = 0.f, e3 = 0.f;
#pragma unroll
    for (int c = 0; c < CC; c++) {
        e0 += __expf(a[c].x - mx0); e1 += __expf(a[c].y - mx1);
        e2 += __expf(a[c].z - mx2); e3 += __expf(a[c].w - mx3);
        g0 = (lab.x == c) ? a[c].x : g0;
        g1 = (lab.y == c) ? a[c].y : g1;
        g2 = (lab.z == c) ? a[c].z : g2;
        g3 = (lab.w == c) ? a[c].w : g3;
    }
    // CE >= 0 mathematically; clamp guards the bit-histogram from sign-bit flukes.
    float l0 = fmaxf(mx0 + __logf(e0) - g0, 0.f);
    float l1 = fmaxf(mx1 + __logf(e1) - g1, 0.f);
    float l2 = fmaxf(mx2 + __logf(e2) - g2, 0.f);
    float l3 = fmaxf(mx3 + __logf(e3) - g3, 0.f);

    float4 o; o.x = l0; o.y = l1; o.z = l2; o.w = l3;
    *(float4*)(loss + pix0) = o;

    atomicAdd(&lh[__float_as_uint(l0) >> 20], 1u);
    atomicAdd(&lh[__float_as_uint(l1) >> 20], 1u);
    atomicAdd(&lh[__float_as_uint(l2) >> 20], 1u);
    atomicAdd(&lh[__float_as_uint(l3) >> 20], 1u);

    __syncthreads();
    for (int i = threadIdx.x; i < 2048; i += 256) {
        uint32_t v = lh[i];
        if (v) atomicAdd(&hist1[b * 2048 + i], v);
    }
}

// ---------- parallel descending radix-select: one block (256 thr) per row ----------

template <int NBINS>
__global__ __launch_bounds__(256) void scan_k(
    const uint32_t* __restrict__ hist, const uint32_t* __restrict__ cntPrev,
    uint32_t* __restrict__ selOut, uint32_t* __restrict__ cntOut)
{
    __shared__ uint32_t wt[4];
    constexpr int CH = NBINS / 256;
    int r = blockIdx.x;
    const uint32_t* hrow = hist + r * NBINS;
    int base = NBINS - CH * ((int)threadIdx.x + 1);   // thread 0 owns TOP bins
    uint32_t hloc[CH];
    uint32_t csum = 0;
#pragma unroll
    for (int i = 0; i < CH; i++) { hloc[i] = hrow[base + i]; csum += hloc[i]; }
    uint32_t incl = block_incl_scan_u32(csum, wt);
    uint32_t pre = incl - csum;                       // count strictly above my chunk
    uint32_t prev = cntPrev ? cntPrev[r] : 0u;
    uint32_t target = (uint32_t)KSEL - prev;
    if (pre < target && pre + csum >= target) {
        uint32_t cum = pre;
#pragma unroll
        for (int i = CH - 1; i >= 0; i--) {
            uint32_t h = hloc[i];
            if (cum + h >= target) { selOut[r] = (uint32_t)(base + i); cntOut[r] = prev + cum; break; }
            cum += h;
        }
    }
}

// ---------- K2: sum-above + mid-12-bit refine ----------

__global__ __launch_bounds__(256) void refine2(
    const float* __restrict__ loss, uint32_t* __restrict__ hist2,
    const uint32_t* __restrict__ sel1, double* __restrict__ sumAbove)
{
    __shared__ uint32_t lh[4096];
    __shared__ double dwt[4];
    for (int i = threadIdx.x; i < 4096; i += 256) lh[i] = 0u;
    __syncthreads();

    int b = blockIdx.x >> 9;
    uint32_t s1 = sel1[b];
    int pix0 = blockIdx.x * 1024 + threadIdx.x * 4;
    float4 v = *(const float4*)(loss + pix0);

    double sum = 0.0;
    {
        float vv[4] = {v.x, v.y, v.z, v.w};
#pragma unroll
        for (int j = 0; j < 4; j++) {
            uint32_t u = __float_as_uint(vv[j]);
            uint32_t t = u >> 20;
            if (t > s1) sum += (double)vv[j];
            else if (t == s1) atomicAdd(&lh[(u >> 8) & 0xFFFu], 1u);
        }
    }
    __syncthreads();
    block_sum_atomic(sum, &sumAbove[b], dwt);
    for (int i = threadIdx.x; i < 4096; i += 256) {
        uint32_t c = lh[i];
        if (c) atomicAdd(&hist2[b * 4096 + i], c);
    }
}

// ---------- K3: low-8-bit refine ----------

__global__ __launch_bounds__(256) void refine3(
    const float* __restrict__ loss, uint32_t* __restrict__ hist3,
    const uint32_t* __restrict__ sel1, const uint32_t* __restrict__ sel2,
    double* __restrict__ sumAbove)
{
    __shared__ uint32_t lh[256];
    __shared__ double dwt[4];
    lh[threadIdx.x] = 0u;
    __syncthreads();

    int b = blockIdx.x >> 9;
    uint32_t s1 = sel1[b], s2 = sel2[b];
    int pix0 = blockIdx.x * 1024 + threadIdx.x * 4;
    float4 v = *(const float4*)(loss + pix0);

    double sum = 0.0;
    {
        float vv[4] = {v.x, v.y, v.z, v.w};
#pragma unroll
        for (int j = 0; j < 4; j++) {
            uint32_t u = __float_as_uint(vv[j]);
            if ((u >> 20) == s1) {
                uint32_t mid = (u >> 8) & 0xFFFu;
                if (mid > s2) sum += (double)vv[j];
                else if (mid == s2) atomicAdd(&lh[u & 0xFFu], 1u);
            }
        }
    }
    __syncthreads();
    block_sum_atomic(sum, &sumAbove[b], dwt);
    {
        uint32_t c = lh[threadIdx.x];
        if (c) atomicAdd(&hist3[b * 256 + threadIdx.x], c);
    }
}

// ---------- finalize: parallel closed-form tie-corrected top-k sum ----------
// hist3 bins are EXACT float bit patterns. Thread t owns bin 255-t.

__global__ __launch_bounds__(256) void finalize_k(
    const uint32_t* __restrict__ hist3,
    const uint32_t* __restrict__ sel1, const uint32_t* __restrict__ sel2,
    const uint32_t* __restrict__ cnt2, const double* __restrict__ sumAbove,
    float* __restrict__ out)
{
    __shared__ uint32_t wt[4];
    __shared__ double dwt[4];
    double tot = 0.0;
    for (int r = 0; r < BB; r++) {
        int b3 = 255 - (int)threadIdx.x;
        uint32_t h = hist3[r * 256 + b3];
        uint32_t incl = block_incl_scan_u32(h, wt);
        uint32_t pre = incl - h;                       // count in bins above b3
        uint32_t rem = (uint32_t)KSEL - cnt2[r];
        uint32_t take = (rem > pre) ? ((rem - pre < h) ? (rem - pre) : h) : 0u;
        uint32_t P = (sel1[r] << 20) | (sel2[r] << 8) | (uint32_t)b3;
        double contrib = (double)take * (double)__uint_as_float(P);
        double s = block_reduce_double(contrib, dwt);
        if (threadIdx.x == 0) tot += s + sumAbove[r];
    }
    if (threadIdx.x == 0) out[0] = (float)(tot / ((double)BB * (double)KSEL));
}

extern "C" void kernel_launch(void* const* d_in, const int* in_sizes, int n_in,
                              void* d_out, int out_size, void* d_ws, size_t ws_size,
                              hipStream_t stream)
{
    const float* logits = (const float*)d_in[0];
    const int* labels   = (const int*)d_in[1];
    float* out          = (float*)d_out;

    char* ws = (char*)d_ws;
    float* loss      = (float*)ws;
    uint32_t* ctrl   = (uint32_t*)(ws + LOSS_BYTES);
    uint32_t* hist1  = ctrl + H1_OFF;
    uint32_t* hist2  = ctrl + H2_OFF;
    uint32_t* hist3  = ctrl + H3_OFF;
    uint32_t* sel1   = ctrl + SEL1_OFF;
    uint32_t* cnt1   = ctrl + CNT1_OFF;
    uint32_t* sel2   = ctrl + SEL2_OFF;
    uint32_t* cnt2   = ctrl + CNT2_OFF;
    double* sumAbove = (double*)(ctrl + SUMA_OFF);

    (void)hipMemsetAsync(ctrl, 0, CTRL_WORDS * sizeof(uint32_t), stream);
    loss_hist1<<<GRID, 256, 0, stream>>>(logits, labels, loss, hist1);
    scan_k<2048><<<BB, 256, 0, stream>>>(hist1, nullptr, sel1, cnt1);
    refine2<<<GRID, 256, 0, stream>>>(loss, hist2, sel1, sumAbove);
    scan_k<4096><<<BB, 256, 0, stream>>>(hist2, cnt1, sel2, cnt2);
    refine3<<<GRID, 256, 0, stream>>>(loss, hist3, sel1, sel2, sumAbove);
    finalize_k<<<1, 256, 0, stream>>>(hist3, sel1, sel2, cnt2, sumAbove, out);
}